// Round 24
// baseline (106.602 us; speedup 1.0000x reference)
//
#include <hip/hip_runtime.h>
#include <math.h>

// B=1, S=2048, E=1024, nh=16, hs=64.
// R21/R23 base (103.8-104.2us) + ONE change: brot folded into the G-gemm
// DISPATCH as extra grid blocks (blockIdx.y==16). Both only read rot_t
// (no dependency between them), so brot hides under the GEMM. One fewer
// launch + gap.
// Pipeline:
//   fused_cast: x->bf16; W_qkv[1024:3072]->w_all kv; W_dense->bf16;
//               rotary^T->rot_t; W_qkv[0:1024]^T->wq_t
//   G-gemm(+brot blocks): w_all[0:1024] = rot_t @ wq_t^T ; b_all = R^T b_q
//   qkv-gemm:   qk[2048][2048] = x @ w_all^T + b_all (cols<1024 scaled
//               0.125*log2e); cols>=2048 -> vt transposed
//   attn:       LDS-staged MFMA flash attn, 4 waves/block, 64 q-rows,
//               split=2 x 1024 keys, raw v_exp_f32 softmax -> partials
//   merge:      y = sum(partials)/sum(l)
//   dense-gemm: out = y @ W_dense^T + b_dense

typedef float  f32x4  __attribute__((ext_vector_type(4)));
typedef __bf16 bf16x8 __attribute__((ext_vector_type(8)));
typedef __bf16 bf16x4 __attribute__((ext_vector_type(4)));

__device__ __forceinline__ unsigned short f2bf(float f) {
    unsigned int u = __builtin_bit_cast(unsigned int, f);
    u += 0x7FFFu + ((u >> 16) & 1u);            // RNE
    return (unsigned short)(u >> 16);
}
__device__ __forceinline__ float bf2f(unsigned short h) {
    return __builtin_bit_cast(float, (unsigned int)h << 16);
}
// raw HW exp2: scores are log2-domain, |s| small -> no denormal fixup needed.
// s_nop 0 covers the CDNA trans->VALU wait state for the inline-asm result.
__device__ __forceinline__ float fast_exp2(float x) {
    float r;
    asm("v_exp_f32 %0, %1\n\ts_nop 0" : "=v"(r) : "v"(x));
    return r;
}
__device__ __forceinline__ void glds16(const unsigned short* g, unsigned short* l) {
    __builtin_amdgcn_global_load_lds(
        (const __attribute__((address_space(1))) void*)g,
        (__attribute__((address_space(3))) void*)l, 16, 0, 0);
}
__device__ __forceinline__ bf16x8 ldfrag(const unsigned short* p) {
    return __builtin_bit_cast(bf16x8, *(const int4*)p);
}

// ---------------------------------------------------------------------------
// bf16 MFMA GEMM, NT: C[M,N] = A[M,K] * B[N,K]^T (+bias).
// SCALE_MODE 1: cols<1024 scaled by 0.125*log2e.
// WRITE_VT: cols>=2048 written transposed to vtout[col-2048][row].
// FUSE_BROT: blocks with blockIdx.y==16 instead compute
//   ball[d<1024] = sum_e A[d][e]*bq[e] (A = rot_t) and copy
//   ball[1024..3071] = bq[1024..3071]; they never touch the GEMM path.
// ---------------------------------------------------------------------------
template <int BM, int BN, int WGM, int WGN, bool OUT_BF16, bool HAS_BIAS,
          int SCALE_MODE, bool WRITE_VT, bool FUSE_BROT>
__global__ __launch_bounds__(256) void gemm_bf16mfma(
    const unsigned short* __restrict__ A, int lda,
    const unsigned short* __restrict__ B, int ldb,
    const float* __restrict__ bias,
    void* __restrict__ Cv, int ldc,
    unsigned short* __restrict__ vtout,
    const float* __restrict__ bq, float* __restrict__ ball, int K)
{
    constexpr int WM = BM / WGM, WN = BN / WGN;
    constexpr int FM = WM / 16, FN = WN / 16;
    __shared__ unsigned short As[BM * 32];
    __shared__ unsigned short Bs[BN * 32];

    const int t    = threadIdx.x;

    if (FUSE_BROT && blockIdx.y == 16) {
        // brot block bx: d = bx*64 + (wave)*16 + i, wave-reduce over e.
        const int bx   = blockIdx.x;         // 0..15
        const int wv   = t >> 6;             // 0..3
        const int l    = t & 63;
#pragma unroll
        for (int i = 0; i < 16; ++i) {
            const int d = bx * 64 + wv * 16 + i;
            float acc = 0.f;
#pragma unroll
            for (int j = 0; j < 16; ++j) {
                const int e = j * 64 + l;
                acc += bf2f(A[(size_t)d * 1024 + e]) * bq[e];   // A = rot_t
            }
#pragma unroll
            for (int off = 1; off < 64; off <<= 1) acc += __shfl_xor(acc, off);
            if (l == 0) ball[d] = acc;
        }
        // copy bq[1024..3071]: 2048 floats over 16 blocks = 128/block
        if (t < 128) {
            const int idx = 1024 + bx * 128 + t;
            ball[idx] = bq[idx];
        }
        return;
    }

    const int lane = t & 63;
    const int wid  = t >> 6;
    const int wr   = wid / WGN;
    const int wc   = wid % WGN;
    const int bm   = blockIdx.y * BM;
    const int bn   = blockIdx.x * BN;

    const int srow = t >> 2;
    const int scol = (t & 3) * 8;
    unsigned short* ldsA = As + (t & 192) * 8;
    unsigned short* ldsB = Bs + (t & 192) * 8;

    const int fr = lane & 15;
    const int fq = lane >> 4;

    f32x4 acc[FM][FN];
#pragma unroll
    for (int i = 0; i < FM; ++i)
#pragma unroll
        for (int j = 0; j < FN; ++j) acc[i][j] = (f32x4){0.f, 0.f, 0.f, 0.f};

    const size_t a_base = (size_t)(bm + srow) * lda + scol;
    const size_t b_base = (size_t)(bn + srow) * ldb + scol;

    for (int k0 = 0; k0 < K; k0 += 32) {
#pragma unroll
        for (int p = 0; p < BM / 64; ++p)
            glds16(A + a_base + (size_t)p * 64 * lda + k0, ldsA + p * 2048);
#pragma unroll
        for (int p = 0; p < BN / 64; ++p)
            glds16(B + b_base + (size_t)p * 64 * ldb + k0, ldsB + p * 2048);
        __syncthreads();

        bf16x8 aF[FM], bF[FN];
#pragma unroll
        for (int m = 0; m < FM; ++m)
            aF[m] = ldfrag(As + (wr * WM + m * 16 + fr) * 32 + fq * 8);
#pragma unroll
        for (int n = 0; n < FN; ++n)
            bF[n] = ldfrag(Bs + (wc * WN + n * 16 + fr) * 32 + fq * 8);
#pragma unroll
        for (int m = 0; m < FM; ++m)
#pragma unroll
            for (int n = 0; n < FN; ++n)
                acc[m][n] = __builtin_amdgcn_mfma_f32_16x16x32_bf16(
                    aF[m], bF[n], acc[m][n], 0, 0, 0);
        __syncthreads();
    }

#pragma unroll
    for (int m = 0; m < FM; ++m) {
        const int row0 = bm + wr * WM + m * 16 + fq * 4;
#pragma unroll
        for (int n = 0; n < FN; ++n) {
            const int col = bn + wc * WN + n * 16 + fr;
            const float bv = HAS_BIAS ? bias[col] : 0.f;
            if (WRITE_VT && col >= 2048) {
                ushort4 o;
                o.x = f2bf(acc[m][n][0] + bv);
                o.y = f2bf(acc[m][n][1] + bv);
                o.z = f2bf(acc[m][n][2] + bv);
                o.w = f2bf(acc[m][n][3] + bv);
                *(ushort4*)&vtout[(size_t)(col - 2048) * 2048 + row0] = o;
            } else {
#pragma unroll
                for (int j = 0; j < 4; ++j) {
                    float v = acc[m][n][j] + bv;
                    if (SCALE_MODE == 1 && col < 1024)
                        v *= 0.18033688011112042f;  // 0.125 * log2(e)
                    if (OUT_BF16)
                        ((unsigned short*)Cv)[(size_t)(row0 + j) * ldc + col] = f2bf(v);
                    else
                        ((float*)Cv)[(size_t)(row0 + j) * ldc + col] = v;
                }
            }
        }
    }
}

// ---------------------------------------------------------------------------
// Fused casts / transposes.
// [0,2048) x->x_bf | [2048,4096) Wqkv rows 1024..3071 -> w_all kv part
// [4096,5120) W_dense->wd_bf | [5120,5376) rotary^T->rot_t
// [5376,5632) Wq rows 0..1023 ^T -> wq_t
// ---------------------------------------------------------------------------
__global__ __launch_bounds__(256) void fused_cast(
    const float* __restrict__ x, const float* __restrict__ Wq,
    const float* __restrict__ Wd, const float* __restrict__ rot,
    unsigned short* __restrict__ x_bf, unsigned short* __restrict__ w_all,
    unsigned short* __restrict__ wd_bf, unsigned short* __restrict__ rot_t,
    unsigned short* __restrict__ wq_t)
{
    __shared__ unsigned short tile[64][68];
    const int b = blockIdx.x;
    const int t = threadIdx.x;

    if (b < 5120) {
        const float4* in;
        ushort4* out;
        int i;
        if (b < 2048) {
            in = (const float4*)x;               out = (ushort4*)x_bf;
            i = b * 256 + t;
        } else if (b < 4096) {
            in = (const float4*)Wq + 262144;     out = (ushort4*)w_all + 262144;
            i = (b - 2048) * 256 + t;
        } else {
            in = (const float4*)Wd;              out = (ushort4*)wd_bf;
            i = (b - 4096) * 256 + t;
        }
        const float4 v = in[i];
        ushort4 o;
        o.x = f2bf(v.x); o.y = f2bf(v.y); o.z = f2bf(v.z); o.w = f2bf(v.w);
        out[i] = o;
        return;
    }

    const bool is_rot = (b < 5376);
    const float* in          = is_rot ? rot   : Wq;
    unsigned short* out      = is_rot ? rot_t : wq_t;
    const int tb = (b - 5120) & 255;
    const int bn = (tb & 15) * 64;
    const int bk = (tb >> 4) * 64;
    const int tr = t >> 4;
    const int tc = (t & 15) * 4;
#pragma unroll
    for (int p = 0; p < 4; ++p) {
        const int r = tr + p * 16;
        const float4 v = *(const float4*)&in[(size_t)(bk + r) * 1024 + bn + tc];
        tile[tc + 0][r] = f2bf(v.x);
        tile[tc + 1][r] = f2bf(v.y);
        tile[tc + 2][r] = f2bf(v.z);
        tile[tc + 3][r] = f2bf(v.w);
    }
    __syncthreads();
#pragma unroll
    for (int p = 0; p < 4; ++p) {
        const int r = tr + p * 16;
        ushort4 o;
        o.x = tile[r][tc + 0];
        o.y = tile[r][tc + 1];
        o.z = tile[r][tc + 2];
        o.w = tile[r][tc + 3];
        *(ushort4*)&out[(size_t)(bn + r) * 1024 + bk + tc] = o;
    }
}

// ---------------------------------------------------------------------------
// LDS-staged MFMA flash attention.
// 4 waves x 16 q-rows = 64 q-rows/block, KVBLK=64, split=2 x 1024 keys.
// Fixed-shift softmax (P = exp2(S)) via raw v_exp_f32.
// K/V double-buffered via global_load_lds, pre-swizzled source, hoisted
// pointer arithmetic (advance by stride per tile).
// ---------------------------------------------------------------------------
__global__ __launch_bounds__(256) void attn_mfma(
    const unsigned short* __restrict__ qk,    // [2048][2048] q|k, q pre-scaled
    const unsigned short* __restrict__ vt,    // [1024][2048]
    unsigned short* __restrict__ partialO,    // [2][2048][1024] bf16
    float* __restrict__ lsum)                 // [2][16][2048]
{
    __shared__ unsigned short Klds[2][4096];  // [key][d] swizzled
    __shared__ unsigned short Vlds[2][4096];  // [d][key] swizzled
    __shared__ unsigned short Plds[4][1024];  // per-wave [q][key] swizzled

    const int t     = threadIdx.x;
    const int lane  = t & 63;
    const int wid   = t >> 6;                 // 0..3
    const int fr    = lane & 15;
    const int fq    = lane >> 4;
    const int q0    = blockIdx.x * 64;
    const int h     = blockIdx.y;
    const int split = blockIdx.z;
    const int ktbase = split * 16;            // 16 tiles of 64 keys

    const int srow = t >> 3;                      // 0..31
    const int soff = 8 * ((t & 7) ^ (srow & 7));  // pre-swizzled source col

    const int fr7_16 = (fr & 7) << 4;
    const int rb0 = ((fq * 16) ^ fr7_16) >> 1;
    const int rb1 = ((64 + fq * 16) ^ fr7_16) >> 1;

    bf16x8 qF[2];
#pragma unroll
    for (int kc = 0; kc < 2; ++kc)
        qF[kc] = ldfrag(&qk[(size_t)(q0 + wid * 16 + fr) * 2048 + h * 64 + kc * 32 + fq * 8]);

    // hoisted staging pointers, advanced by constant stride per tile
    const unsigned short* kg = qk + (size_t)(ktbase * 64 + srow) * 2048 + 1024 + h * 64 + soff;
    const unsigned short* vg = vt + (size_t)(h * 64 + srow) * 2048 + ktbase * 64 + soff;
    unsigned short* const kd = &Klds[0][wid * 512];
    unsigned short* const vd = &Vlds[0][wid * 512];

    auto stage = [&](const unsigned short* kg_, const unsigned short* vg_, int b_) {
        glds16(kg_,             kd + b_ * 4096);
        glds16(kg_ + 32 * 2048, kd + b_ * 4096 + 2048);
        glds16(vg_,             vd + b_ * 4096);
        glds16(vg_ + 32 * 2048, vd + b_ * 4096 + 2048);
    };

    float lrun = 0.f;
    f32x4 oacc[4];
#pragma unroll
    for (int n = 0; n < 4; ++n) oacc[n] = (f32x4){0.f, 0.f, 0.f, 0.f};

    stage(kg, vg, 0);
    kg += 64 * 2048; vg += 64;
    __syncthreads();

    for (int kt = 0; kt < 16; ++kt) {
        const int cb = kt & 1;
        if (kt < 15) {
            stage(kg, vg, cb ^ 1);
            kg += 64 * 2048; vg += 64;
        }

        // ---- S^T = K @ Q^T (log2 units) ----
        f32x4 sacc[4];
        __builtin_amdgcn_s_setprio(1);
#pragma unroll
        for (int m = 0; m < 4; ++m) {
            const bf16x8 a0 = ldfrag(&Klds[cb][(m * 16 + fr) * 64 + rb0]);
            const bf16x8 a1 = ldfrag(&Klds[cb][(m * 16 + fr) * 64 + rb1]);
            sacc[m] = __builtin_amdgcn_mfma_f32_16x16x32_bf16(a0, qF[0],
                          (f32x4){0.f, 0.f, 0.f, 0.f}, 0, 0, 0);
            sacc[m] = __builtin_amdgcn_mfma_f32_16x16x32_bf16(a1, qF[1],
                          sacc[m], 0, 0, 0);
        }
        __builtin_amdgcn_s_setprio(0);

        // ---- fixed-shift softmax: P = exp2(S), raw v_exp_f32 ----
        float ps = 0.f;
#pragma unroll
        for (int m = 0; m < 4; ++m) {
            bf16x4 pk;
            const float p0 = fast_exp2(sacc[m][0]); ps += p0; pk[0] = (__bf16)p0;
            const float p1 = fast_exp2(sacc[m][1]); ps += p1; pk[1] = (__bf16)p1;
            const float p2 = fast_exp2(sacc[m][2]); ps += p2; pk[2] = (__bf16)p2;
            const float p3 = fast_exp2(sacc[m][3]); ps += p3; pk[3] = (__bf16)p3;
            *(ushort4*)&Plds[wid][fr * 64 + (((m * 32 + fq * 8) ^ fr7_16) >> 1)] =
                __builtin_bit_cast(ushort4, pk);
        }
        ps += __shfl_xor(ps, 16);
        ps += __shfl_xor(ps, 32);
        lrun += ps;

        // ---- O += P @ Vt^T ----
        const bf16x8 pa0 = ldfrag(&Plds[wid][fr * 64 + rb0]);
        const bf16x8 pa1 = ldfrag(&Plds[wid][fr * 64 + rb1]);
        __builtin_amdgcn_s_setprio(1);
#pragma unroll
        for (int n = 0; n < 4; ++n) {
            const bf16x8 v0 = ldfrag(&Vlds[cb][(n * 16 + fr) * 64 + rb0]);
            const bf16x8 v1 = ldfrag(&Vlds[cb][(n * 16 + fr) * 64 + rb1]);
            oacc[n] = __builtin_amdgcn_mfma_f32_16x16x32_bf16(pa0, v0, oacc[n], 0, 0, 0);
            oacc[n] = __builtin_amdgcn_mfma_f32_16x16x32_bf16(pa1, v1, oacc[n], 0, 0, 0);
        }
        __builtin_amdgcn_s_setprio(0);

        __syncthreads();   // staged next tile complete; all waves done with cb
    }

    // ---- write unnormalized partial O + l ----
    unsigned short* po = partialO + (size_t)split * 2048 * 1024;
#pragma unroll
    for (int n = 0; n < 4; ++n) {
        const size_t base = (size_t)(q0 + wid * 16 + fq * 4) * 1024 + h * 64 + n * 16 + fr;
        po[base]        = f2bf(oacc[n][0]);
        po[base + 1024] = f2bf(oacc[n][1]);
        po[base + 2048] = f2bf(oacc[n][2]);
        po[base + 3072] = f2bf(oacc[n][3]);
    }
    if (fq == 0)
        lsum[(split * 16 + h) * 2048 + q0 + wid * 16 + fr] = lrun;
}

// ---------------------------------------------------------------------------
// y[s][c] = (O0[s][c] + O1[s][c]) / (l0[h][s] + l1[h][s]),  h = c>>6
// ---------------------------------------------------------------------------
__global__ __launch_bounds__(256) void merge_attn(
    const unsigned short* __restrict__ partialO, const float* __restrict__ lsum,
    unsigned short* __restrict__ y)
{
    const int idx = blockIdx.x * 256 + threadIdx.x;   // 8 elems each
    const int s  = idx >> 7;
    const int h  = (idx & 127) >> 3;
    const float rinv = 1.f / (lsum[h * 2048 + s] + lsum[32768 + h * 2048 + s]);

    union U8 { int4 v; unsigned short u[8]; };
    U8 a0, a1, o;
    a0.v = *(const int4*)&partialO[(size_t)idx * 8];
    a1.v = *(const int4*)&partialO[(size_t)idx * 8 + 2097152];
#pragma unroll
    for (int i = 0; i < 8; ++i)
        o.u[i] = f2bf((bf2f(a0.u[i]) + bf2f(a1.u[i])) * rinv);
    *(int4*)&y[(size_t)idx * 8] = o.v;
}

// ---------------------------------------------------------------------------
extern "C" void kernel_launch(void* const* d_in, const int* in_sizes, int n_in,
                              void* d_out, int out_size, void* d_ws, size_t ws_size,
                              hipStream_t stream)
{
    const float* x       = (const float*)d_in[0];
    const float* W_qkv   = (const float*)d_in[1];
    const float* b_qkv   = (const float*)d_in[2];
    const float* rotary  = (const float*)d_in[3];
    const float* W_dense = (const float*)d_in[4];
    const float* b_dense = (const float*)d_in[5];
    float* out = (float*)d_out;

    char* w = (char*)d_ws;
    // persistent through attn/dense:
    unsigned short* qk_bf   = (unsigned short*)(w);              // 8,388,608 B [2048][2048]
    unsigned short* y_bf    = (unsigned short*)(w + 8388608);    // 4,194,304
    unsigned short* vt      = (unsigned short*)(w + 12582912);   // 4,194,304
    unsigned short* wd_bf   = (unsigned short*)(w + 16777216);   // 2,097,152
    float*          b_all   = (float*)(w + 18874368);            //    12,288
    float*          lsum    = (float*)(w + 18886656);            //   262,144
    // partial O [2][2048][1024] bf16 = 8,388,608 B @ 19410944..27799552.
    // w_all / x_bf / rot_t / wq_t alias in the dead-before-attn region:
    unsigned short* partial = (unsigned short*)(w + 19410944);
    unsigned short* w_all   = (unsigned short*)(w + 19410944);   // 6,291,456
    unsigned short* x_bf    = (unsigned short*)(w + 25702400);   // 4,194,304
    unsigned short* rot_t   = (unsigned short*)(w + 29896704);   // 2,097,152
    unsigned short* wq_t    = (unsigned short*)(w + 31993856);   // 2,097,152
    // total footprint: 34,091,008 B

    fused_cast<<<5632, 256, 0, stream>>>(x, W_qkv, W_dense, rotary,
                                         x_bf, w_all, wd_bf, rot_t, wq_t);

    // G = R^T Wq -> w_all rows 0..1023 ; blocks y==16 compute b_all = R^T b_q
    gemm_bf16mfma<64, 64, 2, 2, true, false, 0, false, true>
        <<<dim3(16, 17), 256, 0, stream>>>(
        rot_t, 1024, wq_t, 1024, nullptr, w_all, 1024, nullptr,
        b_qkv, b_all, 1024);

    // qk = x @ w_all^T + b_all (cols<1024 scaled); cols>=2048 -> vt transposed
    gemm_bf16mfma<64, 128, 2, 2, true, true, 1, true, false>
        <<<dim3(24, 32), 256, 0, stream>>>(
        x_bf, 1024, w_all, 1024, b_all, qk_bf, 2048, vt,
        nullptr, nullptr, 1024);

    // attention: 32 q-tiles x 16 heads x 2 splits, 4-wave staged blocks
    attn_mfma<<<dim3(32, 16, 2), 256, 0, stream>>>(qk_bf, vt, partial, lsum);
    merge_attn<<<1024, 256, 0, stream>>>(partial, lsum, y_bf);

    gemm_bf16mfma<64, 64, 2, 2, false, true, 0, false, false>
        <<<dim3(16, 32), 256, 0, stream>>>(
        y_bf, 1024, wd_bf, 1024, b_dense, out, 1024, nullptr,
        nullptr, nullptr, 1024);
}

// Round 25
// 103.734 us; speedup vs baseline: 1.0277x; 1.0277x over previous
//
#include <hip/hip_runtime.h>
#include <math.h>

// B=1, S=2048, E=1024, nh=16, hs=64.
// FINAL: exact R21/R23-verified configuration (103.8-104.2us, session best).
// R24's brot-into-G-gemm fold regressed (+2.4us): appending 16 brot blocks
// to the exactly-full 256-block G-gemm grid extended the dispatch tail that
// gates the dependent qkv-gemm. Lesson: dispatch fusion must not lengthen
// the critical dispatch's completion.
// Pipeline:
//   fused_cast: x->bf16; W_qkv[1024:3072]->w_all kv; W_dense->bf16;
//               rotary^T->rot_t; W_qkv[0:1024]^T->wq_t
//   brot:       b_all[0:1024] = R^T b_q (coalesced rot_t read); rest copied
//   G-gemm:     w_all[0:1024] = rot_t @ wq_t^T  (folded rotary)
//   qkv-gemm:   qk[2048][2048] = x @ w_all^T + b_all (cols<1024 scaled
//               0.125*log2e); cols>=2048 -> vt transposed
//   attn:       LDS-staged MFMA flash attn, 4 waves/block, 64 q-rows,
//               split=2 x 1024 keys, raw v_exp_f32 softmax -> partials
//   merge:      y = sum(partials)/sum(l)
//   dense-gemm: out = y @ W_dense^T + b_dense

typedef float  f32x4  __attribute__((ext_vector_type(4)));
typedef __bf16 bf16x8 __attribute__((ext_vector_type(8)));
typedef __bf16 bf16x4 __attribute__((ext_vector_type(4)));

__device__ __forceinline__ unsigned short f2bf(float f) {
    unsigned int u = __builtin_bit_cast(unsigned int, f);
    u += 0x7FFFu + ((u >> 16) & 1u);            // RNE
    return (unsigned short)(u >> 16);
}
__device__ __forceinline__ float bf2f(unsigned short h) {
    return __builtin_bit_cast(float, (unsigned int)h << 16);
}
// raw HW exp2: scores are log2-domain, |s| small -> no denormal fixup needed.
// s_nop 0 covers the CDNA trans->VALU wait state for the inline-asm result.
__device__ __forceinline__ float fast_exp2(float x) {
    float r;
    asm("v_exp_f32 %0, %1\n\ts_nop 0" : "=v"(r) : "v"(x));
    return r;
}
__device__ __forceinline__ void glds16(const unsigned short* g, unsigned short* l) {
    __builtin_amdgcn_global_load_lds(
        (const __attribute__((address_space(1))) void*)g,
        (__attribute__((address_space(3))) void*)l, 16, 0, 0);
}
__device__ __forceinline__ bf16x8 ldfrag(const unsigned short* p) {
    return __builtin_bit_cast(bf16x8, *(const int4*)p);
}

// ---------------------------------------------------------------------------
// bf16 MFMA GEMM, NT: C[M,N] = A[M,K] * B[N,K]^T (+bias).
// SCALE_MODE 1: cols<1024 scaled by 0.125*log2e.
// WRITE_VT: cols>=2048 written transposed to vtout[col-2048][row] (b64),
//           and NOT written to C.
// ---------------------------------------------------------------------------
template <int BM, int BN, int WGM, int WGN, bool OUT_BF16, bool HAS_BIAS,
          int SCALE_MODE, bool WRITE_VT>
__global__ __launch_bounds__(256) void gemm_bf16mfma(
    const unsigned short* __restrict__ A, int lda,
    const unsigned short* __restrict__ B, int ldb,
    const float* __restrict__ bias,
    void* __restrict__ Cv, int ldc,
    unsigned short* __restrict__ vtout, int K)
{
    constexpr int WM = BM / WGM, WN = BN / WGN;
    constexpr int FM = WM / 16, FN = WN / 16;
    __shared__ unsigned short As[BM * 32];
    __shared__ unsigned short Bs[BN * 32];

    const int t    = threadIdx.x;
    const int lane = t & 63;
    const int wid  = t >> 6;
    const int wr   = wid / WGN;
    const int wc   = wid % WGN;
    const int bm   = blockIdx.y * BM;
    const int bn   = blockIdx.x * BN;

    const int srow = t >> 2;
    const int scol = (t & 3) * 8;
    unsigned short* ldsA = As + (t & 192) * 8;
    unsigned short* ldsB = Bs + (t & 192) * 8;

    const int fr = lane & 15;
    const int fq = lane >> 4;

    f32x4 acc[FM][FN];
#pragma unroll
    for (int i = 0; i < FM; ++i)
#pragma unroll
        for (int j = 0; j < FN; ++j) acc[i][j] = (f32x4){0.f, 0.f, 0.f, 0.f};

    const size_t a_base = (size_t)(bm + srow) * lda + scol;
    const size_t b_base = (size_t)(bn + srow) * ldb + scol;

    for (int k0 = 0; k0 < K; k0 += 32) {
#pragma unroll
        for (int p = 0; p < BM / 64; ++p)
            glds16(A + a_base + (size_t)p * 64 * lda + k0, ldsA + p * 2048);
#pragma unroll
        for (int p = 0; p < BN / 64; ++p)
            glds16(B + b_base + (size_t)p * 64 * ldb + k0, ldsB + p * 2048);
        __syncthreads();

        bf16x8 aF[FM], bF[FN];
#pragma unroll
        for (int m = 0; m < FM; ++m)
            aF[m] = ldfrag(As + (wr * WM + m * 16 + fr) * 32 + fq * 8);
#pragma unroll
        for (int n = 0; n < FN; ++n)
            bF[n] = ldfrag(Bs + (wc * WN + n * 16 + fr) * 32 + fq * 8);
#pragma unroll
        for (int m = 0; m < FM; ++m)
#pragma unroll
            for (int n = 0; n < FN; ++n)
                acc[m][n] = __builtin_amdgcn_mfma_f32_16x16x32_bf16(
                    aF[m], bF[n], acc[m][n], 0, 0, 0);
        __syncthreads();
    }

#pragma unroll
    for (int m = 0; m < FM; ++m) {
        const int row0 = bm + wr * WM + m * 16 + fq * 4;
#pragma unroll
        for (int n = 0; n < FN; ++n) {
            const int col = bn + wc * WN + n * 16 + fr;
            const float bv = HAS_BIAS ? bias[col] : 0.f;
            if (WRITE_VT && col >= 2048) {
                ushort4 o;
                o.x = f2bf(acc[m][n][0] + bv);
                o.y = f2bf(acc[m][n][1] + bv);
                o.z = f2bf(acc[m][n][2] + bv);
                o.w = f2bf(acc[m][n][3] + bv);
                *(ushort4*)&vtout[(size_t)(col - 2048) * 2048 + row0] = o;
            } else {
#pragma unroll
                for (int j = 0; j < 4; ++j) {
                    float v = acc[m][n][j] + bv;
                    if (SCALE_MODE == 1 && col < 1024)
                        v *= 0.18033688011112042f;  // 0.125 * log2(e)
                    if (OUT_BF16)
                        ((unsigned short*)Cv)[(size_t)(row0 + j) * ldc + col] = f2bf(v);
                    else
                        ((float*)Cv)[(size_t)(row0 + j) * ldc + col] = v;
                }
            }
        }
    }
}

// ---------------------------------------------------------------------------
// Fused casts / transposes.
// [0,2048) x->x_bf | [2048,4096) Wqkv rows 1024..3071 -> w_all kv part
// [4096,5120) W_dense->wd_bf | [5120,5376) rotary^T->rot_t
// [5376,5632) Wq rows 0..1023 ^T -> wq_t
// ---------------------------------------------------------------------------
__global__ __launch_bounds__(256) void fused_cast(
    const float* __restrict__ x, const float* __restrict__ Wq,
    const float* __restrict__ Wd, const float* __restrict__ rot,
    unsigned short* __restrict__ x_bf, unsigned short* __restrict__ w_all,
    unsigned short* __restrict__ wd_bf, unsigned short* __restrict__ rot_t,
    unsigned short* __restrict__ wq_t)
{
    __shared__ unsigned short tile[64][68];
    const int b = blockIdx.x;
    const int t = threadIdx.x;

    if (b < 5120) {
        const float4* in;
        ushort4* out;
        int i;
        if (b < 2048) {
            in = (const float4*)x;               out = (ushort4*)x_bf;
            i = b * 256 + t;
        } else if (b < 4096) {
            in = (const float4*)Wq + 262144;     out = (ushort4*)w_all + 262144;
            i = (b - 2048) * 256 + t;
        } else {
            in = (const float4*)Wd;              out = (ushort4*)wd_bf;
            i = (b - 4096) * 256 + t;
        }
        const float4 v = in[i];
        ushort4 o;
        o.x = f2bf(v.x); o.y = f2bf(v.y); o.z = f2bf(v.z); o.w = f2bf(v.w);
        out[i] = o;
        return;
    }

    const bool is_rot = (b < 5376);
    const float* in          = is_rot ? rot   : Wq;
    unsigned short* out      = is_rot ? rot_t : wq_t;
    const int tb = (b - 5120) & 255;
    const int bn = (tb & 15) * 64;
    const int bk = (tb >> 4) * 64;
    const int tr = t >> 4;
    const int tc = (t & 15) * 4;
#pragma unroll
    for (int p = 0; p < 4; ++p) {
        const int r = tr + p * 16;
        const float4 v = *(const float4*)&in[(size_t)(bk + r) * 1024 + bn + tc];
        tile[tc + 0][r] = f2bf(v.x);
        tile[tc + 1][r] = f2bf(v.y);
        tile[tc + 2][r] = f2bf(v.z);
        tile[tc + 3][r] = f2bf(v.w);
    }
    __syncthreads();
#pragma unroll
    for (int p = 0; p < 4; ++p) {
        const int r = tr + p * 16;
        ushort4 o;
        o.x = tile[r][tc + 0];
        o.y = tile[r][tc + 1];
        o.z = tile[r][tc + 2];
        o.w = tile[r][tc + 3];
        *(ushort4*)&out[(size_t)(bn + r) * 1024 + bk + tc] = o;
    }
}

// ---------------------------------------------------------------------------
// b_all[d<1024] = sum_e rot_t[d][e] * b_qkv[e]  (coalesced rot_t read)
// b_all[1024..3071] = b_qkv[1024..3071]
// ---------------------------------------------------------------------------
__global__ __launch_bounds__(256) void brot_kernel(
    const unsigned short* __restrict__ rot_t, const float* __restrict__ b_qkv,
    float* __restrict__ b_all)
{
    const int b = blockIdx.x;
    const int t = threadIdx.x;
    if (b < 256) {
        const int d = b * 4 + (t >> 6);
        const int l = t & 63;
        float acc = 0.f;
#pragma unroll
        for (int i = 0; i < 16; ++i) {
            const int e = i * 64 + l;
            acc += bf2f(rot_t[(size_t)d * 1024 + e]) * b_qkv[e];
        }
#pragma unroll
        for (int off = 1; off < 64; off <<= 1) acc += __shfl_xor(acc, off);
        if (l == 0) b_all[d] = acc;
    } else {
        const int idx = 1024 + (b - 256) * 256 + t;
        b_all[idx] = b_qkv[idx];
    }
}

// ---------------------------------------------------------------------------
// LDS-staged MFMA flash attention.
// 4 waves x 16 q-rows = 64 q-rows/block, KVBLK=64, split=2 x 1024 keys.
// Fixed-shift softmax (P = exp2(S)) via raw v_exp_f32.
// K/V double-buffered via global_load_lds, pre-swizzled source, hoisted
// pointer arithmetic (advance by stride per tile).
// ---------------------------------------------------------------------------
__global__ __launch_bounds__(256) void attn_mfma(
    const unsigned short* __restrict__ qk,    // [2048][2048] q|k, q pre-scaled
    const unsigned short* __restrict__ vt,    // [1024][2048]
    unsigned short* __restrict__ partialO,    // [2][2048][1024] bf16
    float* __restrict__ lsum)                 // [2][16][2048]
{
    __shared__ unsigned short Klds[2][4096];  // [key][d] swizzled
    __shared__ unsigned short Vlds[2][4096];  // [d][key] swizzled
    __shared__ unsigned short Plds[4][1024];  // per-wave [q][key] swizzled

    const int t     = threadIdx.x;
    const int lane  = t & 63;
    const int wid   = t >> 6;                 // 0..3
    const int fr    = lane & 15;
    const int fq    = lane >> 4;
    const int q0    = blockIdx.x * 64;
    const int h     = blockIdx.y;
    const int split = blockIdx.z;
    const int ktbase = split * 16;            // 16 tiles of 64 keys

    const int srow = t >> 3;                      // 0..31
    const int soff = 8 * ((t & 7) ^ (srow & 7));  // pre-swizzled source col

    const int fr7_16 = (fr & 7) << 4;
    const int rb0 = ((fq * 16) ^ fr7_16) >> 1;
    const int rb1 = ((64 + fq * 16) ^ fr7_16) >> 1;

    bf16x8 qF[2];
#pragma unroll
    for (int kc = 0; kc < 2; ++kc)
        qF[kc] = ldfrag(&qk[(size_t)(q0 + wid * 16 + fr) * 2048 + h * 64 + kc * 32 + fq * 8]);

    // hoisted staging pointers, advanced by constant stride per tile
    const unsigned short* kg = qk + (size_t)(ktbase * 64 + srow) * 2048 + 1024 + h * 64 + soff;
    const unsigned short* vg = vt + (size_t)(h * 64 + srow) * 2048 + ktbase * 64 + soff;
    unsigned short* const kd = &Klds[0][wid * 512];
    unsigned short* const vd = &Vlds[0][wid * 512];

    auto stage = [&](const unsigned short* kg_, const unsigned short* vg_, int b_) {
        glds16(kg_,             kd + b_ * 4096);
        glds16(kg_ + 32 * 2048, kd + b_ * 4096 + 2048);
        glds16(vg_,             vd + b_ * 4096);
        glds16(vg_ + 32 * 2048, vd + b_ * 4096 + 2048);
    };

    float lrun = 0.f;
    f32x4 oacc[4];
#pragma unroll
    for (int n = 0; n < 4; ++n) oacc[n] = (f32x4){0.f, 0.f, 0.f, 0.f};

    stage(kg, vg, 0);
    kg += 64 * 2048; vg += 64;
    __syncthreads();

    for (int kt = 0; kt < 16; ++kt) {
        const int cb = kt & 1;
        if (kt < 15) {
            stage(kg, vg, cb ^ 1);
            kg += 64 * 2048; vg += 64;
        }

        // ---- S^T = K @ Q^T (log2 units) ----
        f32x4 sacc[4];
        __builtin_amdgcn_s_setprio(1);
#pragma unroll
        for (int m = 0; m < 4; ++m) {
            const bf16x8 a0 = ldfrag(&Klds[cb][(m * 16 + fr) * 64 + rb0]);
            const bf16x8 a1 = ldfrag(&Klds[cb][(m * 16 + fr) * 64 + rb1]);
            sacc[m] = __builtin_amdgcn_mfma_f32_16x16x32_bf16(a0, qF[0],
                          (f32x4){0.f, 0.f, 0.f, 0.f}, 0, 0, 0);
            sacc[m] = __builtin_amdgcn_mfma_f32_16x16x32_bf16(a1, qF[1],
                          sacc[m], 0, 0, 0);
        }
        __builtin_amdgcn_s_setprio(0);

        // ---- fixed-shift softmax: P = exp2(S), raw v_exp_f32 ----
        float ps = 0.f;
#pragma unroll
        for (int m = 0; m < 4; ++m) {
            bf16x4 pk;
            const float p0 = fast_exp2(sacc[m][0]); ps += p0; pk[0] = (__bf16)p0;
            const float p1 = fast_exp2(sacc[m][1]); ps += p1; pk[1] = (__bf16)p1;
            const float p2 = fast_exp2(sacc[m][2]); ps += p2; pk[2] = (__bf16)p2;
            const float p3 = fast_exp2(sacc[m][3]); ps += p3; pk[3] = (__bf16)p3;
            *(ushort4*)&Plds[wid][fr * 64 + (((m * 32 + fq * 8) ^ fr7_16) >> 1)] =
                __builtin_bit_cast(ushort4, pk);
        }
        ps += __shfl_xor(ps, 16);
        ps += __shfl_xor(ps, 32);
        lrun += ps;

        // ---- O += P @ Vt^T ----
        const bf16x8 pa0 = ldfrag(&Plds[wid][fr * 64 + rb0]);
        const bf16x8 pa1 = ldfrag(&Plds[wid][fr * 64 + rb1]);
        __builtin_amdgcn_s_setprio(1);
#pragma unroll
        for (int n = 0; n < 4; ++n) {
            const bf16x8 v0 = ldfrag(&Vlds[cb][(n * 16 + fr) * 64 + rb0]);
            const bf16x8 v1 = ldfrag(&Vlds[cb][(n * 16 + fr) * 64 + rb1]);
            oacc[n] = __builtin_amdgcn_mfma_f32_16x16x32_bf16(pa0, v0, oacc[n], 0, 0, 0);
            oacc[n] = __builtin_amdgcn_mfma_f32_16x16x32_bf16(pa1, v1, oacc[n], 0, 0, 0);
        }
        __builtin_amdgcn_s_setprio(0);

        __syncthreads();   // staged next tile complete; all waves done with cb
    }

    // ---- write unnormalized partial O + l ----
    unsigned short* po = partialO + (size_t)split * 2048 * 1024;
#pragma unroll
    for (int n = 0; n < 4; ++n) {
        const size_t base = (size_t)(q0 + wid * 16 + fq * 4) * 1024 + h * 64 + n * 16 + fr;
        po[base]        = f2bf(oacc[n][0]);
        po[base + 1024] = f2bf(oacc[n][1]);
        po[base + 2048] = f2bf(oacc[n][2]);
        po[base + 3072] = f2bf(oacc[n][3]);
    }
    if (fq == 0)
        lsum[(split * 16 + h) * 2048 + q0 + wid * 16 + fr] = lrun;
}

// ---------------------------------------------------------------------------
// y[s][c] = (O0[s][c] + O1[s][c]) / (l0[h][s] + l1[h][s]),  h = c>>6
// ---------------------------------------------------------------------------
__global__ __launch_bounds__(256) void merge_attn(
    const unsigned short* __restrict__ partialO, const float* __restrict__ lsum,
    unsigned short* __restrict__ y)
{
    const int idx = blockIdx.x * 256 + threadIdx.x;   // 8 elems each
    const int s  = idx >> 7;
    const int h  = (idx & 127) >> 3;
    const float rinv = 1.f / (lsum[h * 2048 + s] + lsum[32768 + h * 2048 + s]);

    union U8 { int4 v; unsigned short u[8]; };
    U8 a0, a1, o;
    a0.v = *(const int4*)&partialO[(size_t)idx * 8];
    a1.v = *(const int4*)&partialO[(size_t)idx * 8 + 2097152];
#pragma unroll
    for (int i = 0; i < 8; ++i)
        o.u[i] = f2bf((bf2f(a0.u[i]) + bf2f(a1.u[i])) * rinv);
    *(int4*)&y[(size_t)idx * 8] = o.v;
}

// ---------------------------------------------------------------------------
extern "C" void kernel_launch(void* const* d_in, const int* in_sizes, int n_in,
                              void* d_out, int out_size, void* d_ws, size_t ws_size,
                              hipStream_t stream)
{
    const float* x       = (const float*)d_in[0];
    const float* W_qkv   = (const float*)d_in[1];
    const float* b_qkv   = (const float*)d_in[2];
    const float* rotary  = (const float*)d_in[3];
    const float* W_dense = (const float*)d_in[4];
    const float* b_dense = (const float*)d_in[5];
    float* out = (float*)d_out;

    char* w = (char*)d_ws;
    // persistent through attn/dense:
    unsigned short* qk_bf   = (unsigned short*)(w);              // 8,388,608 B [2048][2048]
    unsigned short* y_bf    = (unsigned short*)(w + 8388608);    // 4,194,304
    unsigned short* vt      = (unsigned short*)(w + 12582912);   // 4,194,304
    unsigned short* wd_bf   = (unsigned short*)(w + 16777216);   // 2,097,152
    float*          b_all   = (float*)(w + 18874368);            //    12,288
    float*          lsum    = (float*)(w + 18886656);            //   262,144
    // partial O [2][2048][1024] bf16 = 8,388,608 B @ 19410944..27799552.
    // w_all / x_bf / rot_t / wq_t alias in the dead-before-attn region:
    unsigned short* partial = (unsigned short*)(w + 19410944);
    unsigned short* w_all   = (unsigned short*)(w + 19410944);   // 6,291,456
    unsigned short* x_bf    = (unsigned short*)(w + 25702400);   // 4,194,304
    unsigned short* rot_t   = (unsigned short*)(w + 29896704);   // 2,097,152
    unsigned short* wq_t    = (unsigned short*)(w + 31993856);   // 2,097,152
    // total footprint: 34,091,008 B

    fused_cast<<<5632, 256, 0, stream>>>(x, W_qkv, W_dense, rotary,
                                         x_bf, w_all, wd_bf, rot_t, wq_t);
    brot_kernel<<<264, 256, 0, stream>>>(rot_t, b_qkv, b_all);

    // G = R^T Wq -> w_all rows 0..1023
    gemm_bf16mfma<64, 64, 2, 2, true, false, 0, false>
        <<<dim3(16, 16), 256, 0, stream>>>(
        rot_t, 1024, wq_t, 1024, nullptr, w_all, 1024, nullptr, 1024);

    // qk = x @ w_all^T + b_all (cols<1024 scaled); cols>=2048 -> vt transposed
    gemm_bf16mfma<64, 128, 2, 2, true, true, 1, true>
        <<<dim3(24, 32), 256, 0, stream>>>(
        x_bf, 1024, w_all, 1024, b_all, qk_bf, 2048, vt, 1024);

    // attention: 32 q-tiles x 16 heads x 2 splits, 4-wave staged blocks
    attn_mfma<<<dim3(32, 16, 2), 256, 0, stream>>>(qk_bf, vt, partial, lsum);
    merge_attn<<<1024, 256, 0, stream>>>(partial, lsum, y_bf);

    gemm_bf16mfma<64, 64, 2, 2, false, true, 0, false>
        <<<dim3(16, 32), 256, 0, stream>>>(
        y_bf, 1024, wd_bf, 1024, b_dense, out, 1024, nullptr, 1024);
}